// Round 2
// baseline (1227.688 us; speedup 1.0000x reference)
//
#include <hip/hip_runtime.h>
#include <math.h>

#define C 128

__device__ __forceinline__ float gelu_f(float v) {
    // exact gelu: v * 0.5 * (1 + erf(v/sqrt(2)))
    return 0.5f * v * (1.0f + erff(v * 0.70710678118654752f));
}

// ---------------------------------------------------------------------------
// Weight prep: Wc[l] = self_w[l] @ gate_w1[l][:128,:]   (128x128)
//              bc[l] = self_b[l] @ gate_w1[l][:128,:] + gate_b1[l]
// grid (129, L), block 128. blockIdx.x==128 computes the bias row.
// ---------------------------------------------------------------------------
__global__ void prep_weights_kernel(const float* __restrict__ self_w,
                                    const float* __restrict__ self_b,
                                    const float* __restrict__ gate_w1,
                                    const float* __restrict__ gate_b1,
                                    float* __restrict__ Wc, float* __restrict__ bc) {
    const int l = blockIdx.y;
    const int i = blockIdx.x;
    const int j = threadIdx.x;
    const float* gw = gate_w1 + l * 256 * C;  // top half rows 0..127
    if (i < C) {
        const float* sw = self_w + l * C * C + i * C;
        float s = 0.f;
        for (int k = 0; k < C; ++k) s += sw[k] * gw[k * C + j];
        Wc[l * C * C + i * C + j] = s;
    } else {
        const float* sb = self_b + l * C;
        float s = gate_b1[l * C + j];
        for (int k = 0; k < C; ++k) s += sb[k] * gw[k * C + j];
        bc[l * C + j] = s;
    }
}

// ---------------------------------------------------------------------------
// Lift hidden: hid[n][c] = gelu( sum_f x[n,3+f] * w1[f][c] + b1[c] ),  f<6
// ---------------------------------------------------------------------------
__global__ void lift_hidden_kernel(const float* __restrict__ x,
                                   const float* __restrict__ w1,
                                   const float* __restrict__ b1,
                                   float* __restrict__ hid, int N) {
    int idx = blockIdx.x * 256 + threadIdx.x;
    if (idx >= N * C) return;
    int n = idx >> 7, c = idx & 127;
    const float* xr = x + n * 9 + 3;
    float s = b1[c];
#pragma unroll
    for (int f = 0; f < 6; ++f) s += xr[f] * w1[f * C + c];
    hid[idx] = gelu_f(s);
}

// ---------------------------------------------------------------------------
// Generic 128-wide fp32 GEMM: out = maybe_gelu(A0@W0 [+ A1@W1] + bias) [+ resid]
// K=128 per source. BM=128, BN=128, BK=64, 256 thr, 8x8 micro-tile.
// ---------------------------------------------------------------------------
__global__ __launch_bounds__(256, 2)
void gemm128_kernel(const float* __restrict__ A0, const float* __restrict__ W0,
                    const float* __restrict__ A1, const float* __restrict__ W1,
                    const float* __restrict__ bias, const float* __restrict__ resid,
                    float* __restrict__ out, int M, int act) {
    __shared__ float As[128][64];
    __shared__ float Ws[64][128];
    const int t = threadIdx.x;
    const int m0 = blockIdx.x * 128;
    const int rg = (t >> 4) << 3;   // row group 0..120
    const int cg = (t & 15) << 3;   // col group 0..120

    float acc[8][8];
#pragma unroll
    for (int i = 0; i < 8; ++i)
#pragma unroll
        for (int j = 0; j < 8; ++j) acc[i][j] = 0.f;

    for (int src = 0; src < 2; ++src) {
        const float* A = src ? A1 : A0;
        const float* W = src ? W1 : W0;
        if (!A) break;
        for (int kk = 0; kk < 2; ++kk) {
            // stage A tile [128][64]
#pragma unroll
            for (int j = 0; j < 8; ++j) {
                int idx = t + 256 * j;         // 0..2047 float4 slots
                int r = idx >> 4;
                int k4 = (idx & 15) << 2;
                float4 v = make_float4(0.f, 0.f, 0.f, 0.f);
                int m = m0 + r;
                if (m < M) v = *(const float4*)&A[m * C + kk * 64 + k4];
                *(float4*)&As[r][k4] = v;
            }
            // stage W slab [64][128] (contiguous copy)
            const float* Wsl = W + kk * 64 * C;
            float* Wf = &Ws[0][0];
#pragma unroll
            for (int j = 0; j < 8; ++j) {
                int idx = (t + 256 * j) << 2;
                *(float4*)&Wf[idx] = *(const float4*)&Wsl[idx];
            }
            __syncthreads();
#pragma unroll
            for (int k4 = 0; k4 < 16; ++k4) {
                float4 a[8];
#pragma unroll
                for (int i = 0; i < 8; ++i) a[i] = *(const float4*)&As[rg + i][k4 << 2];
#pragma unroll
                for (int j = 0; j < 4; ++j) {
                    float4 wl = *(const float4*)&Ws[(k4 << 2) + j][cg];
                    float4 wh = *(const float4*)&Ws[(k4 << 2) + j][cg + 4];
#pragma unroll
                    for (int i = 0; i < 8; ++i) {
                        float av = (j == 0) ? a[i].x : (j == 1) ? a[i].y
                                 : (j == 2) ? a[i].z : a[i].w;
                        acc[i][0] += av * wl.x; acc[i][1] += av * wl.y;
                        acc[i][2] += av * wl.z; acc[i][3] += av * wl.w;
                        acc[i][4] += av * wh.x; acc[i][5] += av * wh.y;
                        acc[i][6] += av * wh.z; acc[i][7] += av * wh.w;
                    }
                }
            }
            __syncthreads();
        }
    }

    float bl[8];
#pragma unroll
    for (int j = 0; j < 8; ++j) bl[j] = bias[cg + j];
#pragma unroll
    for (int i = 0; i < 8; ++i) {
        int m = m0 + rg + i;
        if (m < M) {
            float o[8];
#pragma unroll
            for (int j = 0; j < 8; ++j) {
                float v = acc[i][j] + bl[j];
                if (act) v = gelu_f(v);
                o[j] = v;
            }
            if (resid) {
#pragma unroll
                for (int j = 0; j < 8; ++j) o[j] += resid[m * C + cg + j];
            }
            *(float4*)&out[m * C + cg]     = make_float4(o[0], o[1], o[2], o[3]);
            *(float4*)&out[m * C + cg + 4] = make_float4(o[4], o[5], o[6], o[7]);
        }
    }
}

// ---------------------------------------------------------------------------
// CSR build
// ---------------------------------------------------------------------------
__global__ void zero_i32_kernel(int* __restrict__ p, int n) {
    int i = blockIdx.x * 256 + threadIdx.x;
    if (i < n) p[i] = 0;
}

__global__ void deg_count_kernel(const int* __restrict__ row, int* __restrict__ deg, int E) {
    int e = blockIdx.x * 256 + threadIdx.x;
    if (e < E) atomicAdd(&deg[row[e]], 1);
}

// k1: per-1024 chunk inclusive scan -> offs[i+1], partial sums -> part[b]
__global__ void scan_chunk_kernel(const int* __restrict__ deg, int* __restrict__ offs,
                                  int* __restrict__ part, int N) {
    __shared__ int ts[256];
    const int t = threadIdx.x;
    const int base = blockIdx.x * 1024 + t * 4;
    int v0 = (base + 0 < N) ? deg[base + 0] : 0;
    int v1 = (base + 1 < N) ? deg[base + 1] : 0;
    int v2 = (base + 2 < N) ? deg[base + 2] : 0;
    int v3 = (base + 3 < N) ? deg[base + 3] : 0;
    int l0 = v0, l1 = l0 + v1, l2 = l1 + v2, l3 = l2 + v3;
    ts[t] = l3;
    __syncthreads();
    for (int d = 1; d < 256; d <<= 1) {
        int add = (t >= d) ? ts[t - d] : 0;
        __syncthreads();
        ts[t] += add;
        __syncthreads();
    }
    int tex = ts[t] - l3;  // exclusive prefix of this thread within block
    if (base + 0 < N) offs[base + 1] = tex + l0;
    if (base + 1 < N) offs[base + 2] = tex + l1;
    if (base + 2 < N) offs[base + 3] = tex + l2;
    if (base + 3 < N) offs[base + 4] = tex + l3;
    if (t == 255) part[blockIdx.x] = ts[255];
}

// k2: exclusive scan of partials (n <= 128), single block of 128
__global__ void scan_partials_kernel(int* __restrict__ part, int n) {
    __shared__ int s[128];
    const int t = threadIdx.x;
    int v = (t < n) ? part[t] : 0;
    s[t] = v;
    __syncthreads();
    for (int d = 1; d < 128; d <<= 1) {
        int add = (t >= d) ? s[t - d] : 0;
        __syncthreads();
        s[t] += add;
        __syncthreads();
    }
    if (t < n) part[t] = s[t] - v;
}

// k3: add block offsets; set offs[0]=0; cursor[i] = final offs[i]
__global__ void scan_add_kernel(int* __restrict__ offs, const int* __restrict__ part,
                                int* __restrict__ cursor, int N) {
    const int t = threadIdx.x;
    const int base = blockIdx.x * 1024 + t * 4;
    const int add = part[blockIdx.x];
#pragma unroll
    for (int j = 0; j < 4; ++j) {
        int i = base + j;
        if (i < N) {
            int v = offs[i + 1] + add;
            offs[i + 1] = v;
            if (i + 1 < N) cursor[i + 1] = v;
        }
    }
    if (blockIdx.x == 0 && t == 0) {
        offs[0] = 0;
        cursor[0] = 0;
    }
}

__global__ void fill_kernel(const int* __restrict__ row, const int* __restrict__ col,
                            const float* __restrict__ ev, int* __restrict__ cursor,
                            int2* __restrict__ epack, int E) {
    int e = blockIdx.x * 256 + threadIdx.x;
    if (e >= E) return;
    int r = row[e];
    int pos = atomicAdd(&cursor[r], 1);
    int2 p;
    p.x = col[e];
    p.y = __float_as_int(ev[e]);
    epack[pos] = p;
}

// ---------------------------------------------------------------------------
// Aggregation (gather form): one wave per node, lane = 2 channels.
// Unrolled x2: two independent edge loads in flight per iteration.
// ---------------------------------------------------------------------------
__global__ __launch_bounds__(256)
void aggregate_kernel(const float* __restrict__ nb, const int* __restrict__ offs,
                      const int2* __restrict__ epack, float* __restrict__ aggr, int N) {
    const int lane = threadIdx.x & 63;
    const int node = (blockIdx.x << 2) + (threadIdx.x >> 6);
    if (node >= N) return;
    const int s = offs[node], e = offs[node + 1];
    const int ch = lane << 1;
    float ax = 0.f, ay = 0.f, bx = 0.f, by = 0.f;
    int i = s;
    for (; i + 2 <= e; i += 2) {
        int2 p0 = epack[i];
        int2 p1 = epack[i + 1];
        float v0 = __int_as_float(p0.y);
        float v1 = __int_as_float(p1.y);
        float2 x0 = *(const float2*)&nb[p0.x * C + ch];
        float2 x1 = *(const float2*)&nb[p1.x * C + ch];
        ax += v0 * x0.x; ay += v0 * x0.y;
        bx += v1 * x1.x; by += v1 * x1.y;
    }
    if (i < e) {
        int2 p = epack[i];
        float v = __int_as_float(p.y);
        float2 xv = *(const float2*)&nb[p.x * C + ch];
        ax += v * xv.x; ay += v * xv.y;
    }
    float2 o;
    o.x = ax + bx;
    o.y = ay + by;
    *(float2*)&aggr[node * C + ch] = o;
}

// ---------------------------------------------------------------------------
// LayerNorm over C=128, one wave per node, in place on h
// ---------------------------------------------------------------------------
__global__ __launch_bounds__(256)
void layernorm_kernel(float* __restrict__ h, const float* __restrict__ g,
                      const float* __restrict__ b, int N) {
    const int lane = threadIdx.x & 63;
    const int node = (blockIdx.x << 2) + (threadIdx.x >> 6);
    if (node >= N) return;
    float2 v = *(const float2*)&h[node * C + (lane << 1)];
    float s = v.x + v.y;
#pragma unroll
    for (int m = 1; m < 64; m <<= 1) s += __shfl_xor(s, m, 64);
    float mu = s * (1.f / 128.f);
    float dx = v.x - mu, dy = v.y - mu;
    float q = dx * dx + dy * dy;
#pragma unroll
    for (int m = 1; m < 64; m <<= 1) q += __shfl_xor(q, m, 64);
    float rs = 1.f / sqrtf(q * (1.f / 128.f) + 1e-5f);
    float2 gg = *(const float2*)&g[lane << 1];
    float2 bb = *(const float2*)&b[lane << 1];
    float2 o;
    o.x = dx * rs * gg.x + bb.x;
    o.y = dy * rs * gg.y + bb.y;
    *(float2*)&h[node * C + (lane << 1)] = o;
}

// ---------------------------------------------------------------------------
extern "C" void kernel_launch(void* const* d_in, const int* in_sizes, int n_in,
                              void* d_out, int out_size, void* d_ws, size_t ws_size,
                              hipStream_t stream) {
    const float* x    = (const float*)d_in[0];
    const int*   ei   = (const int*)d_in[1];
    const float* ev   = (const float*)d_in[2];
    const float* lw1  = (const float*)d_in[3];
    const float* lb1  = (const float*)d_in[4];
    const float* lw2  = (const float*)d_in[5];
    const float* lb2  = (const float*)d_in[6];
    const float* sw   = (const float*)d_in[7];
    const float* sb   = (const float*)d_in[8];
    const float* nw   = (const float*)d_in[9];
    const float* nbi  = (const float*)d_in[10];
    const float* gw1  = (const float*)d_in[11];
    const float* gb1  = (const float*)d_in[12];
    const float* gw2  = (const float*)d_in[13];
    const float* gb2  = (const float*)d_in[14];
    const float* ng   = (const float*)d_in[15];
    const float* nbt  = (const float*)d_in[16];

    const int N = in_sizes[0] / 9;
    const int E = in_sizes[2];
    const int L = in_sizes[7] / (C * C);
    const int* row = ei;
    const int* col = ei + E;

    float* h = (float*)d_out;  // N*C

    // workspace carve (16B-aligned chunks first)
    char* p = (char*)d_ws;
    float* tmp  = (float*)p; p += (size_t)N * C * sizeof(float);
    float* aggr = (float*)p; p += (size_t)N * C * sizeof(float);
    int2*  epack = (int2*)p; p += (size_t)E * sizeof(int2);
    float* Wc   = (float*)p; p += (size_t)L * C * C * sizeof(float);
    float* bc   = (float*)p; p += (size_t)L * C * sizeof(float);
    int*   deg  = (int*)p;   p += (size_t)N * sizeof(int);
    int*   offs = (int*)p;   p += (size_t)(N + 1) * sizeof(int);
    int*   cursor = (int*)p; p += (size_t)N * sizeof(int);
    int*   part = (int*)p;   p += 1024 * sizeof(int);

    const int NB_SCAN = (N + 1023) / 1024;  // 98 for N=100000 (<=128 required)
    const int GB_NODE = (N + 3) / 4;
    const int GB_EDGE = (E + 255) / 256;
    const int GB_GEMM = (N + 127) / 128;

    // prep combined weights
    prep_weights_kernel<<<dim3(C + 1, L), C, 0, stream>>>(sw, sb, gw1, gb1, Wc, bc);

    // lift
    lift_hidden_kernel<<<(N * C + 255) / 256, 256, 0, stream>>>(x, lw1, lb1, tmp, N);
    gemm128_kernel<<<GB_GEMM, 256, 0, stream>>>(tmp, lw2, nullptr, nullptr, lb2,
                                                nullptr, h, N, 0);

    // CSR build
    zero_i32_kernel<<<(N + 255) / 256, 256, 0, stream>>>(deg, N);
    deg_count_kernel<<<GB_EDGE, 256, 0, stream>>>(row, deg, E);
    scan_chunk_kernel<<<NB_SCAN, 256, 0, stream>>>(deg, offs, part, N);
    scan_partials_kernel<<<1, 128, 0, stream>>>(part, NB_SCAN);
    scan_add_kernel<<<NB_SCAN, 256, 0, stream>>>(offs, part, cursor, N);
    fill_kernel<<<GB_EDGE, 256, 0, stream>>>(row, col, ev, cursor, epack, E);

    for (int l = 0; l < L; ++l) {
        const float* nwl  = nw  + (size_t)l * C * C;
        const float* nbl  = nbi + (size_t)l * C;
        const float* Wcl  = Wc  + (size_t)l * C * C;
        const float* bcl  = bc  + (size_t)l * C;
        const float* gw1b = gw1 + (size_t)l * 2 * C * C + (size_t)C * C;  // bottom half
        const float* gw2l = gw2 + (size_t)l * C * C;
        const float* gb2l = gb2 + (size_t)l * C;

        // neighbor = h @ neigh_w + neigh_b
        gemm128_kernel<<<GB_GEMM, 256, 0, stream>>>(h, nwl, nullptr, nullptr, nbl,
                                                    nullptr, tmp, N, 0);
        // aggr = CSR-gather(neighbor)
        aggregate_kernel<<<GB_NODE, 256, 0, stream>>>(tmp, offs, epack, aggr, N);
        // u1 = gelu(h @ Wc + aggr @ gw1_bot + bc)
        gemm128_kernel<<<GB_GEMM, 256, 0, stream>>>(h, Wcl, aggr, gw1b, bcl,
                                                    nullptr, tmp, N, 1);
        // h = h + u1 @ gw2 + gb2
        gemm128_kernel<<<GB_GEMM, 256, 0, stream>>>(tmp, gw2l, nullptr, nullptr, gb2l,
                                                    h, h, N, 0);
    }

    layernorm_kernel<<<GB_NODE, 256, 0, stream>>>(h, ng, nbt, N);
}

// Round 4
// 853.771 us; speedup vs baseline: 1.4380x; 1.4380x over previous
//
#include <hip/hip_runtime.h>
#include <math.h>

#define C 128

typedef unsigned short u16;
typedef __attribute__((ext_vector_type(8))) short short8;
typedef __attribute__((ext_vector_type(4))) float f32x4;

__device__ __forceinline__ float gelu_f(float v) {
    return 0.5f * v * (1.0f + erff(v * 0.70710678118654752f));
}

// bf16 helpers (RNE)
__device__ __forceinline__ u16 f2bf(float f) {
    unsigned u = __float_as_uint(f);
    unsigned r = (u + 0x7fffu + ((u >> 16) & 1u)) >> 16;
    return (u16)r;
}
__device__ __forceinline__ float b2f(u16 u) {
    return __uint_as_float(((unsigned)u) << 16);
}

__device__ __forceinline__ void g2lds16(const void* g, void* l) {
    __builtin_amdgcn_global_load_lds(
        (const __attribute__((address_space(1))) unsigned int*)g,
        (__attribute__((address_space(3))) unsigned int*)l, 16, 0, 0);
}

// ---------------------------------------------------------------------------
// Weight prep: Wc[l] = self_w[l] @ gate_w1_top[l]; bc[l] = self_b[l]@gw1_top + gate_b1[l]
// ---------------------------------------------------------------------------
__global__ void prep_weights_kernel(const float* __restrict__ self_w,
                                    const float* __restrict__ self_b,
                                    const float* __restrict__ gate_w1,
                                    const float* __restrict__ gate_b1,
                                    float* __restrict__ Wc, float* __restrict__ bc) {
    const int l = blockIdx.y;
    const int i = blockIdx.x;
    const int j = threadIdx.x;
    const float* gw = gate_w1 + l * 256 * C;  // top half rows 0..127
    if (i < C) {
        const float* sw = self_w + l * C * C + i * C;
        float s = 0.f;
        for (int k = 0; k < C; ++k) s += sw[k] * gw[k * C + j];
        Wc[l * C * C + i * C + j] = s;
    } else {
        const float* sb = self_b + l * C;
        float s = gate_b1[l * C + j];
        for (int k = 0; k < C; ++k) s += sb[k] * gw[k * C + j];
        bc[l * C + j] = s;
    }
}

// ---------------------------------------------------------------------------
// Split+transpose all 9 128x128 weight mats into bf16 hi/lo planes Wt[col][k].
// mats: 0=lw2, 1+l=nw[l], 3+l=gw1_bot[l], 5+l=gw2[l], 7+l=Wc[l]
// grid (128 cols, 9 mats), block 128 (k)
// ---------------------------------------------------------------------------
__global__ void wsplit_kernel(const float* __restrict__ lw2, const float* __restrict__ nw,
                              const float* __restrict__ gw1, const float* __restrict__ gw2,
                              const float* __restrict__ Wc,
                              u16* __restrict__ wh, u16* __restrict__ wl) {
    const int col = blockIdx.x;
    const int mat = blockIdx.y;
    const int k = threadIdx.x;
    const float* src;
    if (mat == 0)      src = lw2;
    else if (mat <= 2) src = nw + (size_t)(mat - 1) * 16384;
    else if (mat <= 4) src = gw1 + (size_t)(mat - 3) * 32768 + 16384;
    else if (mat <= 6) src = gw2 + (size_t)(mat - 5) * 16384;
    else               src = Wc + (size_t)(mat - 7) * 16384;
    float v = src[k * C + col];
    u16 hi = f2bf(v);
    size_t di = (size_t)mat * 16384 + (size_t)col * C + k;
    wh[di] = hi;
    wl[di] = f2bf(v - b2f(hi));
}

// ---------------------------------------------------------------------------
// Lift hidden: planes of gelu(x[:,3:9] @ w1 + b1)
// ---------------------------------------------------------------------------
__global__ void lift_hidden_kernel(const float* __restrict__ x,
                                   const float* __restrict__ w1,
                                   const float* __restrict__ b1,
                                   u16* __restrict__ oh, u16* __restrict__ ol, int N) {
    int idx = blockIdx.x * 256 + threadIdx.x;
    if (idx >= N * C) return;
    int n = idx >> 7, c = idx & 127;
    const float* xr = x + n * 9 + 3;
    float s = b1[c];
#pragma unroll
    for (int f = 0; f < 6; ++f) s += xr[f] * w1[f * C + c];
    s = gelu_f(s);
    u16 hi = f2bf(s);
    oh[idx] = hi;
    ol[idx] = f2bf(s - b2f(hi));
}

// ---------------------------------------------------------------------------
// bf16x3 MFMA GEMM: out = maybe_gelu(sum_src A@W + bias) [+ resid], all operands
// as bf16 hi/lo planes. A: [M][128] planes; W: [col][k] transposed planes.
// BM=128, BN=128, BK=64 (2 rounds/src), 256 thr = 4 waves, each 64x64.
// LDS 64KB -> 2 blocks/CU. XOR-swizzled (T2) via pre-swizzled global source.
// ---------------------------------------------------------------------------
__global__ __launch_bounds__(256, 2)
void gemm_mfma_kernel(const u16* __restrict__ A0h, const u16* __restrict__ A0l,
                      const u16* __restrict__ W0h, const u16* __restrict__ W0l,
                      const u16* __restrict__ A1h, const u16* __restrict__ A1l,
                      const u16* __restrict__ W1h, const u16* __restrict__ W1l,
                      const float* __restrict__ bias,
                      const u16* __restrict__ Rh, const u16* __restrict__ Rl,
                      u16* __restrict__ Oh, u16* __restrict__ Ol,
                      int M, int nsrc, int act) {
    __shared__ u16 lds[4][128 * 64];  // Ahi, Alo, Whi, Wlo half-tiles (16KB each)
    const int t = threadIdx.x;
    const int l = t & 63;
    const int w = t >> 6;
    const int wr = w >> 1, wc = w & 1;
    const int m0 = blockIdx.x * 128;
    const int kg = l >> 4;        // 0..3
    const int swz = l & 7;
    const int l15 = l & 15;

    f32x4 acc[4][4];
#pragma unroll
    for (int m = 0; m < 4; ++m)
#pragma unroll
        for (int n = 0; n < 4; ++n) acc[m][n] = (f32x4)(0.f);

    for (int sidx = 0; sidx < nsrc; ++sidx) {
        const u16* Ah = sidx ? A1h : A0h;
        const u16* Al = sidx ? A1l : A0l;
        const u16* Wh = sidx ? W1h : W0h;
        const u16* Wl = sidx ? W1l : W0l;
        for (int kh = 0; kh < 2; ++kh) {
            // stage 4 half-planes; LDS linear dest, pre-swizzled global source
            const u16* gp[4] = {Ah, Al, Wh, Wl};
#pragma unroll
            for (int p = 0; p < 4; ++p) {
#pragma unroll
                for (int it = 0; it < 4; ++it) {
                    int chunk = it * 256 + t;            // 0..1023
                    int row = chunk >> 3;                // 0..127
                    int cl = (chunk & 7) ^ (row & 7);    // logical chunk
                    int grow = (p < 2) ? ((m0 + row < M) ? m0 + row : M - 1) : row;
                    const u16* src = gp[p] + (size_t)grow * C + kh * 64 + cl * 8;
                    g2lds16(src, &lds[p][chunk * 8]);
                }
            }
            __syncthreads();
#pragma unroll
            for (int s = 0; s < 2; ++s) {
                const int ci = ((s * 4 + kg) ^ swz) * 16;  // swizzled byte-chunk
                short8 ah[4], al[4], bh[4], bl[4];
#pragma unroll
                for (int m = 0; m < 4; ++m) {
                    int ro = (wr * 64 + m * 16 + l15) * 128;  // row byte offset
                    ah[m] = *(const short8*)((const char*)&lds[0][0] + ro + ci);
                    al[m] = *(const short8*)((const char*)&lds[1][0] + ro + ci);
                }
#pragma unroll
                for (int n = 0; n < 4; ++n) {
                    int ro = (wc * 64 + n * 16 + l15) * 128;
                    bh[n] = *(const short8*)((const char*)&lds[2][0] + ro + ci);
                    bl[n] = *(const short8*)((const char*)&lds[3][0] + ro + ci);
                }
#pragma unroll
                for (int m = 0; m < 4; ++m)
#pragma unroll
                    for (int n = 0; n < 4; ++n)
                        acc[m][n] = __builtin_amdgcn_mfma_f32_16x16x32_bf16(ah[m], bh[n], acc[m][n], 0, 0, 0);
#pragma unroll
                for (int m = 0; m < 4; ++m)
#pragma unroll
                    for (int n = 0; n < 4; ++n)
                        acc[m][n] = __builtin_amdgcn_mfma_f32_16x16x32_bf16(al[m], bh[n], acc[m][n], 0, 0, 0);
#pragma unroll
                for (int m = 0; m < 4; ++m)
#pragma unroll
                    for (int n = 0; n < 4; ++n)
                        acc[m][n] = __builtin_amdgcn_mfma_f32_16x16x32_bf16(ah[m], bl[n], acc[m][n], 0, 0, 0);
            }
            __syncthreads();
        }
    }

    // epilogue: bias (+gelu) (+resid hi/lo) -> hi/lo planes
    float bj[4];
#pragma unroll
    for (int n = 0; n < 4; ++n) bj[n] = bias[wc * 64 + n * 16 + l15];
#pragma unroll
    for (int m = 0; m < 4; ++m) {
#pragma unroll
        for (int r = 0; r < 4; ++r) {
            int row = m0 + wr * 64 + m * 16 + kg * 4 + r;
            if (row < M) {
#pragma unroll
                for (int n = 0; n < 4; ++n) {
                    int col = wc * 64 + n * 16 + l15;
                    float o = acc[m][n][r] + bj[n];
                    if (act) o = gelu_f(o);
                    size_t idx = (size_t)row * C + col;
                    if (Rh) o += b2f(Rh[idx]) + b2f(Rl[idx]);
                    u16 hi = f2bf(o);
                    Oh[idx] = hi;
                    Ol[idx] = f2bf(o - b2f(hi));
                }
            }
        }
    }
}

// ---------------------------------------------------------------------------
// CSR build
// ---------------------------------------------------------------------------
__global__ void zero_i32_kernel(int* __restrict__ p, int n) {
    int i = blockIdx.x * 256 + threadIdx.x;
    if (i < n) p[i] = 0;
}

__global__ void deg_count_kernel(const int* __restrict__ row, int* __restrict__ deg, int E) {
    int e = blockIdx.x * 256 + threadIdx.x;
    if (e < E) atomicAdd(&deg[row[e]], 1);
}

__global__ void scan_chunk_kernel(const int* __restrict__ deg, int* __restrict__ offs,
                                  int* __restrict__ part, int N) {
    __shared__ int ts[256];
    const int t = threadIdx.x;
    const int base = blockIdx.x * 1024 + t * 4;
    int v0 = (base + 0 < N) ? deg[base + 0] : 0;
    int v1 = (base + 1 < N) ? deg[base + 1] : 0;
    int v2 = (base + 2 < N) ? deg[base + 2] : 0;
    int v3 = (base + 3 < N) ? deg[base + 3] : 0;
    int l0 = v0, l1 = l0 + v1, l2 = l1 + v2, l3 = l2 + v3;
    ts[t] = l3;
    __syncthreads();
    for (int d = 1; d < 256; d <<= 1) {
        int add = (t >= d) ? ts[t - d] : 0;
        __syncthreads();
        ts[t] += add;
        __syncthreads();
    }
    int tex = ts[t] - l3;
    if (base + 0 < N) offs[base + 1] = tex + l0;
    if (base + 1 < N) offs[base + 2] = tex + l1;
    if (base + 2 < N) offs[base + 3] = tex + l2;
    if (base + 3 < N) offs[base + 4] = tex + l3;
    if (t == 255) part[blockIdx.x] = ts[255];
}

__global__ void scan_partials_kernel(int* __restrict__ part, int n) {
    __shared__ int s[128];
    const int t = threadIdx.x;
    int v = (t < n) ? part[t] : 0;
    s[t] = v;
    __syncthreads();
    for (int d = 1; d < 128; d <<= 1) {
        int add = (t >= d) ? s[t - d] : 0;
        __syncthreads();
        s[t] += add;
        __syncthreads();
    }
    if (t < n) part[t] = s[t] - v;
}

__global__ void scan_add_kernel(int* __restrict__ offs, const int* __restrict__ part,
                                int* __restrict__ cursor, int N) {
    const int t = threadIdx.x;
    const int base = blockIdx.x * 1024 + t * 4;
    const int add = part[blockIdx.x];
#pragma unroll
    for (int j = 0; j < 4; ++j) {
        int i = base + j;
        if (i < N) {
            int v = offs[i + 1] + add;
            offs[i + 1] = v;
            if (i + 1 < N) cursor[i + 1] = v;
        }
    }
    if (blockIdx.x == 0 && t == 0) {
        offs[0] = 0;
        cursor[0] = 0;
    }
}

__global__ void fill_kernel(const int* __restrict__ row, const int* __restrict__ col,
                            const float* __restrict__ ev, int* __restrict__ cursor,
                            int2* __restrict__ epack, int E) {
    int e = blockIdx.x * 256 + threadIdx.x;
    if (e >= E) return;
    int r = row[e];
    int pos = atomicAdd(&cursor[r], 1);
    int2 p;
    p.x = col[e];
    p.y = __float_as_int(ev[e]);
    epack[pos] = p;
}

// ---------------------------------------------------------------------------
// Aggregation (gather): one wave per node, lane = 2 channels, hi/lo planes io.
// ---------------------------------------------------------------------------
__global__ __launch_bounds__(256)
void aggregate_kernel(const u16* __restrict__ nh, const u16* __restrict__ nl,
                      const int* __restrict__ offs, const int2* __restrict__ epack,
                      u16* __restrict__ oh, u16* __restrict__ ol, int N) {
    const int lane = threadIdx.x & 63;
    const int node = (blockIdx.x << 2) + (threadIdx.x >> 6);
    if (node >= N) return;
    const int s = offs[node], e = offs[node + 1];
    const int ch = lane << 1;
    float ax = 0.f, ay = 0.f, bx = 0.f, by = 0.f;
    int i = s;
    for (; i + 2 <= e; i += 2) {
        int2 p0 = epack[i];
        int2 p1 = epack[i + 1];
        float v0 = __int_as_float(p0.y);
        float v1 = __int_as_float(p1.y);
        ushort2 h0 = *(const ushort2*)&nh[(size_t)p0.x * C + ch];
        ushort2 l0 = *(const ushort2*)&nl[(size_t)p0.x * C + ch];
        ushort2 h1 = *(const ushort2*)&nh[(size_t)p1.x * C + ch];
        ushort2 l1 = *(const ushort2*)&nl[(size_t)p1.x * C + ch];
        ax += v0 * (b2f(h0.x) + b2f(l0.x));
        ay += v0 * (b2f(h0.y) + b2f(l0.y));
        bx += v1 * (b2f(h1.x) + b2f(l1.x));
        by += v1 * (b2f(h1.y) + b2f(l1.y));
    }
    if (i < e) {
        int2 p = epack[i];
        float v = __int_as_float(p.y);
        ushort2 h0 = *(const ushort2*)&nh[(size_t)p.x * C + ch];
        ushort2 l0 = *(const ushort2*)&nl[(size_t)p.x * C + ch];
        ax += v * (b2f(h0.x) + b2f(l0.x));
        ay += v * (b2f(h0.y) + b2f(l0.y));
    }
    float sx = ax + bx, sy = ay + by;
    ushort2 ho, lo;
    ho.x = f2bf(sx); ho.y = f2bf(sy);
    lo.x = f2bf(sx - b2f(ho.x)); lo.y = f2bf(sy - b2f(ho.y));
    size_t idx = (size_t)node * C + ch;
    *(ushort2*)&oh[idx] = ho;
    *(ushort2*)&ol[idx] = lo;
}

// ---------------------------------------------------------------------------
// LayerNorm: read h planes, write fp32 d_out
// ---------------------------------------------------------------------------
__global__ __launch_bounds__(256)
void layernorm_kernel(const u16* __restrict__ hh, const u16* __restrict__ hl,
                      const float* __restrict__ g, const float* __restrict__ b,
                      float* __restrict__ out, int N) {
    const int lane = threadIdx.x & 63;
    const int node = (blockIdx.x << 2) + (threadIdx.x >> 6);
    if (node >= N) return;
    size_t idx = (size_t)node * C + (lane << 1);
    ushort2 vh = *(const ushort2*)&hh[idx];
    ushort2 vl = *(const ushort2*)&hl[idx];
    float vx = b2f(vh.x) + b2f(vl.x);
    float vy = b2f(vh.y) + b2f(vl.y);
    float s = vx + vy;
#pragma unroll
    for (int m = 1; m < 64; m <<= 1) s += __shfl_xor(s, m, 64);
    float mu = s * (1.f / 128.f);
    float dx = vx - mu, dy = vy - mu;
    float q = dx * dx + dy * dy;
#pragma unroll
    for (int m = 1; m < 64; m <<= 1) q += __shfl_xor(q, m, 64);
    float rs = 1.f / sqrtf(q * (1.f / 128.f) + 1e-5f);
    float2 gg = *(const float2*)&g[lane << 1];
    float2 bb = *(const float2*)&b[lane << 1];
    float2 o;
    o.x = dx * rs * gg.x + bb.x;
    o.y = dy * rs * gg.y + bb.y;
    *(float2*)&out[idx] = o;
}

// ---------------------------------------------------------------------------
extern "C" void kernel_launch(void* const* d_in, const int* in_sizes, int n_in,
                              void* d_out, int out_size, void* d_ws, size_t ws_size,
                              hipStream_t stream) {
    const float* x    = (const float*)d_in[0];
    const int*   ei   = (const int*)d_in[1];
    const float* ev   = (const float*)d_in[2];
    const float* lw1  = (const float*)d_in[3];
    const float* lb1  = (const float*)d_in[4];
    const float* lw2  = (const float*)d_in[5];
    const float* lb2  = (const float*)d_in[6];
    const float* sw   = (const float*)d_in[7];
    const float* sb   = (const float*)d_in[8];
    const float* nw   = (const float*)d_in[9];
    const float* nbi  = (const float*)d_in[10];
    const float* gw1  = (const float*)d_in[11];
    const float* gb1  = (const float*)d_in[12];
    const float* gw2  = (const float*)d_in[13];
    const float* gb2  = (const float*)d_in[14];
    const float* ng   = (const float*)d_in[15];
    const float* nbt  = (const float*)d_in[16];

    const int N = in_sizes[0] / 9;
    const int E = in_sizes[2];
    const int L = in_sizes[7] / (C * C);
    const int* row = ei;
    const int* col = ei + E;

    float* out = (float*)d_out;

    // workspace carve
    char* p = (char*)d_ws;
    u16* Hh = (u16*)p; p += (size_t)N * C * 2;   // h planes
    u16* Hl = (u16*)p; p += (size_t)N * C * 2;
    u16* Bh = (u16*)p; p += (size_t)N * C * 2;   // hid / neighbor-tmp / u1 planes
    u16* Bl = (u16*)p; p += (size_t)N * C * 2;
    u16* Ch = (u16*)p; p += (size_t)N * C * 2;   // aggr planes
    u16* Cl = (u16*)p; p += (size_t)N * C * 2;
    int2* epack = (int2*)p; p += (size_t)E * sizeof(int2);
    float* Wc = (float*)p; p += (size_t)L * C * C * sizeof(float);
    float* bc = (float*)p; p += (size_t)L * C * sizeof(float);
    u16* wh = (u16*)p; p += (size_t)9 * C * C * 2;
    u16* wl = (u16*)p; p += (size_t)9 * C * C * 2;
    int* deg    = (int*)p; p += (size_t)N * sizeof(int);
    int* offs   = (int*)p; p += (size_t)(N + 1) * sizeof(int);
    int* cursor = (int*)p; p += (size_t)N * sizeof(int);
    int* part   = (int*)p; p += 1024 * sizeof(int);

    const int NB_SCAN = (N + 1023) / 1024;
    const int GB_NODE = (N + 3) / 4;
    const int GB_EDGE = (E + 255) / 256;
    const int GB_GEMM = (N + 127) / 128;

    // weight prep (fp32 Wc, then transpose+split all mats to bf16 planes)
    prep_weights_kernel<<<dim3(C + 1, L), C, 0, stream>>>(sw, sb, gw1, gb1, Wc, bc);
    wsplit_kernel<<<dim3(C, 9), C, 0, stream>>>(lw2, nw, gw1, gw2, Wc, wh, wl);

    // lift
    lift_hidden_kernel<<<(N * C + 255) / 256, 256, 0, stream>>>(x, lw1, lb1, Bh, Bl, N);
    gemm_mfma_kernel<<<GB_GEMM, 256, 0, stream>>>(
        Bh, Bl, wh, wl, nullptr, nullptr, nullptr, nullptr,
        lb2, nullptr, nullptr, Hh, Hl, N, 1, 0);

    // CSR build
    zero_i32_kernel<<<(N + 255) / 256, 256, 0, stream>>>(deg, N);
    deg_count_kernel<<<GB_EDGE, 256, 0, stream>>>(row, deg, E);
    scan_chunk_kernel<<<NB_SCAN, 256, 0, stream>>>(deg, offs, part, N);
    scan_partials_kernel<<<1, 128, 0, stream>>>(part, NB_SCAN);
    scan_add_kernel<<<NB_SCAN, 256, 0, stream>>>(offs, part, cursor, N);
    fill_kernel<<<GB_EDGE, 256, 0, stream>>>(row, col, ev, cursor, epack, E);

    for (int l = 0; l < L; ++l) {
        const u16* nwh  = wh + (size_t)(1 + l) * 16384;
        const u16* nwl_ = wl + (size_t)(1 + l) * 16384;
        const u16* g1h  = wh + (size_t)(3 + l) * 16384;
        const u16* g1l  = wl + (size_t)(3 + l) * 16384;
        const u16* g2h  = wh + (size_t)(5 + l) * 16384;
        const u16* g2l  = wl + (size_t)(5 + l) * 16384;
        const u16* wch  = wh + (size_t)(7 + l) * 16384;
        const u16* wcl  = wl + (size_t)(7 + l) * 16384;

        // neighbor = h @ nw + nb  -> B planes
        gemm_mfma_kernel<<<GB_GEMM, 256, 0, stream>>>(
            Hh, Hl, nwh, nwl_, nullptr, nullptr, nullptr, nullptr,
            nbi + (size_t)l * C, nullptr, nullptr, Bh, Bl, N, 1, 0);
        // aggr = CSR-gather(B) -> C planes
        aggregate_kernel<<<GB_NODE, 256, 0, stream>>>(Bh, Bl, offs, epack, Ch, Cl, N);
        // u1 = gelu(h@Wc + aggr@gw1_bot + bc) -> B planes
        gemm_mfma_kernel<<<GB_GEMM, 256, 0, stream>>>(
            Hh, Hl, wch, wcl, Ch, Cl, g1h, g1l,
            bc + (size_t)l * C, nullptr, nullptr, Bh, Bl, N, 2, 1);
        // h = h + u1@gw2 + gb2 -> H planes (elementwise in-place safe)
        gemm_mfma_kernel<<<GB_GEMM, 256, 0, stream>>>(
            Bh, Bl, g2h, g2l, nullptr, nullptr, nullptr, nullptr,
            gb2 + (size_t)l * C, Hh, Hl, Hh, Hl, N, 1, 0);
    }

    layernorm_kernel<<<GB_NODE, 256, 0, stream>>>(Hh, Hl, ng, nbt, out, N);
}